// Round 6
// baseline (242.681 us; speedup 1.0000x reference)
//
#include <hip/hip_runtime.h>
#include <math.h>

#define HF 128
#define WPAD 136      // padded LDS row stride (bf16 elems): 272 B = 16B-multiple, 2-way banks only (free)

typedef short bfrag __attribute__((ext_vector_type(8)));   // 8 bf16 (4 VGPRs) - MFMA A/B frag
typedef float facc  __attribute__((ext_vector_type(4)));   // 4 f32 - MFMA C/D frag
typedef float f4v   __attribute__((ext_vector_type(4)));   // float4 (for nontemporal builtins)

__device__ __forceinline__ unsigned short f2bf(float x) {
    unsigned int u = __float_as_uint(x);
    unsigned int r = (u + 0x7FFFu + ((u >> 16) & 1u)) >> 16;
    return (unsigned short)r;
}
__device__ __forceinline__ float bflo(unsigned int u) { return __uint_as_float(u << 16); }
__device__ __forceinline__ float bfhi(unsigned int u) { return __uint_as_float(u & 0xffff0000u); }

__device__ __forceinline__ float ssp(float x) {
    const float SHIFT = 0.69314718055994531f;
    return (x > 0.f) ? (x + log1pf(expf(-x)) - SHIFT)
                     : (log1pf(expf(x)) - SHIFT);
}

// ---------------------------------------------------------------------------
// CSR build: histogram -> scan (counts preserved; used as cursor later)
// ---------------------------------------------------------------------------
__global__ void hist_kernel(const int* __restrict__ tgt, int* __restrict__ counts, int E) {
    int eid = blockIdx.x * blockDim.x + threadIdx.x;
    if (eid < E) atomicAdd(&counts[tgt[eid]], 1);
}

__global__ __launch_bounds__(1024) void scan1_kernel(const int* __restrict__ counts,
                                                     int* __restrict__ offsets,
                                                     int* __restrict__ bsum, int N) {
    __shared__ int ws[16];
    int t = threadIdx.x;
    int i = blockIdx.x * 1024 + t;
    int lane = t & 63, wv = t >> 6;
    int val = (i < N) ? counts[i] : 0;
    int x = val;
    #pragma unroll
    for (int d = 1; d < 64; d <<= 1) {
        int y = __shfl_up(x, d, 64);
        if (lane >= d) x += y;
    }
    if (lane == 63) ws[wv] = x;
    __syncthreads();
    if (wv == 0) {
        int s = (lane < 16) ? ws[lane] : 0;
        #pragma unroll
        for (int d = 1; d < 16; d <<= 1) {
            int y = __shfl_up(s, d, 64);
            if (lane >= d) s += y;
        }
        if (lane < 16) ws[lane] = s;
    }
    __syncthreads();
    int pre = ((wv > 0) ? ws[wv - 1] : 0) + (x - val);
    if (i < N) offsets[i] = pre;
    if (t == 0) bsum[blockIdx.x] = ws[15];
}

__global__ __launch_bounds__(1024) void scan23_kernel(int* __restrict__ offsets,
                                                      const int* __restrict__ bsum,
                                                      int N, int E, int nb) {
    __shared__ int pre_s;
    int t = threadIdx.x;
    if (t < 64) {
        int v = (t < nb && t < (int)blockIdx.x) ? bsum[t] : 0;
        #pragma unroll
        for (int d = 32; d > 0; d >>= 1) v += __shfl_down(v, d, 64);
        if (t == 0) pre_s = v;
    }
    __syncthreads();
    int i = blockIdx.x * 1024 + t;
    if (i < N) offsets[i] += pre_s;
    if (blockIdx.x == 0 && t == 0) offsets[N] = E;
}

// ---------------------------------------------------------------------------
// Stream e (f32, nontemporal, sequential), convert rows to bf16, scatter each
// 256 B row into its exact CSR slot. One half-wave (32 lanes) per edge.
// counts doubles as cursor: atomicSub yields a unique slot in [0, count).
// ---------------------------------------------------------------------------
__global__ __launch_bounds__(256) void scatter_convert_kernel(
        const float* __restrict__ e, const int* __restrict__ tgt,
        const int* __restrict__ offsets, int* __restrict__ counts,
        unsigned short* __restrict__ es, int E) {
    int wave = (blockIdx.x * blockDim.x + threadIdx.x) >> 6;
    int lane = threadIdx.x & 63;
    int half = lane >> 5, l32 = lane & 31;
    int eid = wave * 2 + half;
    if (eid >= E) return;
    int t = tgt[eid];
    int pos = 0;
    if (l32 == 0) pos = atomicSub(&counts[t], 1) - 1;
    pos = __shfl(pos, 0, 32);        // broadcast each half-wave's lane-0 value
    int slot = offsets[t] + pos;
    f4v r = __builtin_nontemporal_load((const f4v*)(e + (size_t)eid * HF) + l32);
    ushort4 o;
    o.x = f2bf(r.x); o.y = f2bf(r.y); o.z = f2bf(r.z); o.w = f2bf(r.w);
    ((ushort4*)(es + (size_t)slot * HF))[l32] = o;
}

// ---------------------------------------------------------------------------
// Sequential gather: one wave per node; its rows are contiguous in es.
// Lane holds features 2*lane, 2*lane+1 (u32 = bf16x2). 8-deep load batches.
// ---------------------------------------------------------------------------
__global__ __launch_bounds__(256) void gather_seq_kernel(
        const unsigned short* __restrict__ es, const int* __restrict__ offsets,
        unsigned short* __restrict__ aggb, int N) {
    int node = (blockIdx.x * blockDim.x + threadIdx.x) >> 6;
    if (node >= N) return;
    int lane = threadIdx.x & 63;
    const unsigned int* rp = (const unsigned int*)es;   // row j at j*64 + lane
    int beg = offsets[node], end = offsets[node + 1];
    float s0 = 0.f, s1 = 0.f, t0 = 0.f, t1 = 0.f;
    float u0 = 0.f, u1 = 0.f, v0 = 0.f, v1 = 0.f;
    int j = beg;
    for (; j + 8 <= end; j += 8) {
        unsigned int a0 = rp[(size_t)(j + 0) * 64 + lane];
        unsigned int a1 = rp[(size_t)(j + 1) * 64 + lane];
        unsigned int a2 = rp[(size_t)(j + 2) * 64 + lane];
        unsigned int a3 = rp[(size_t)(j + 3) * 64 + lane];
        unsigned int a4 = rp[(size_t)(j + 4) * 64 + lane];
        unsigned int a5 = rp[(size_t)(j + 5) * 64 + lane];
        unsigned int a6 = rp[(size_t)(j + 6) * 64 + lane];
        unsigned int a7 = rp[(size_t)(j + 7) * 64 + lane];
        s0 += bflo(a0); s1 += bfhi(a0);
        t0 += bflo(a1); t1 += bfhi(a1);
        u0 += bflo(a2); u1 += bfhi(a2);
        v0 += bflo(a3); v1 += bfhi(a3);
        s0 += bflo(a4); s1 += bfhi(a4);
        t0 += bflo(a5); t1 += bfhi(a5);
        u0 += bflo(a6); u1 += bfhi(a6);
        v0 += bflo(a7); v1 += bfhi(a7);
    }
    if (j + 4 <= end) {
        unsigned int a0 = rp[(size_t)(j + 0) * 64 + lane];
        unsigned int a1 = rp[(size_t)(j + 1) * 64 + lane];
        unsigned int a2 = rp[(size_t)(j + 2) * 64 + lane];
        unsigned int a3 = rp[(size_t)(j + 3) * 64 + lane];
        s0 += bflo(a0); s1 += bfhi(a0);
        t0 += bflo(a1); t1 += bfhi(a1);
        u0 += bflo(a2); u1 += bfhi(a2);
        v0 += bflo(a3); v1 += bfhi(a3);
        j += 4;
    }
    if (j + 2 <= end) {
        unsigned int a0 = rp[(size_t)(j + 0) * 64 + lane];
        unsigned int a1 = rp[(size_t)(j + 1) * 64 + lane];
        s0 += bflo(a0); s1 += bfhi(a0);
        t0 += bflo(a1); t1 += bfhi(a1);
        j += 2;
    }
    if (j < end) {
        unsigned int a0 = rp[(size_t)j * 64 + lane];
        s0 += bflo(a0); s1 += bfhi(a0);
    }
    s0 += t0 + u0 + v0;
    s1 += t1 + u1 + v1;
    unsigned int out = ((unsigned int)f2bf(s1) << 16) | (unsigned int)f2bf(s0);
    ((unsigned int*)aggb)[(size_t)node * 64 + lane] = out;
}

// ---------------------------------------------------------------------------
// MFMA MLP: out = v + ( ssp(agg @ w1 + b1) @ w2 + b2 )
// 512 thr (8 waves), 128-node tiles. wave w: rows (w&3)*32, cols (w>>2)*64.
// 16x16x32 bf16 MFMA; C/D: col=lane&15, row=4*(lane>>4)+i  [guide m89].
// ---------------------------------------------------------------------------
__global__ __launch_bounds__(512) void mlp_mfma_kernel(
        const unsigned short* __restrict__ aggb,
        const float* __restrict__ v,
        const float* __restrict__ w1, const float* __restrict__ b1,
        const float* __restrict__ w2, const float* __restrict__ b2,
        float* __restrict__ out, int N, int ngroups) {
    __shared__ unsigned short wt1[HF * WPAD];    // w1 transposed: wt1[n][k], 34 KB
    __shared__ unsigned short wt2[HF * WPAD];    // 34 KB
    __shared__ unsigned short atile[HF * WPAD];  // agg tile, reused for h tile (34 KB)

    int tid = threadIdx.x;
    for (int idx = tid; idx < HF * HF; idx += 512) {
        int k = idx >> 7, n = idx & 127;
        wt1[n * WPAD + k] = f2bf(w1[idx]);
        wt2[n * WPAD + k] = f2bf(w2[idx]);
    }

    int w = tid >> 6, lane = tid & 63;
    int wr = (w & 3) * 32;       // row block base
    int wchalf = (w >> 2) * 64;  // col half base
    int lr = lane & 15;
    int kg = lane >> 4;          // k-group 0..3
    float bias1[4], bias2[4];
    #pragma unroll
    for (int nt = 0; nt < 4; ++nt) {
        int col = wchalf + nt * 16 + lr;
        bias1[nt] = b1[col];
        bias2[nt] = b2[col];
    }

    for (int g = blockIdx.x; g < ngroups; g += gridDim.x) {
        int base = g * HF;
        __syncthreads();   // previous iteration's tile reads done (covers weight staging, 1st iter)

        for (int idx = tid; idx < HF * 16; idx += 512) {
            int r = idx >> 4, c = idx & 15;
            int row = base + r;
            bfrag val = {0,0,0,0,0,0,0,0};
            if (row < N) val = *(const bfrag*)(aggb + (size_t)row * HF + c * 8);
            *(bfrag*)(atile + r * WPAD + c * 8) = val;
        }
        __syncthreads();

        // pass A: h = ssp(agg @ w1 + b1)
        facc acc[2][4];
        #pragma unroll
        for (int m = 0; m < 2; ++m)
            #pragma unroll
            for (int nt = 0; nt < 4; ++nt)
                acc[m][nt] = (facc){0.f, 0.f, 0.f, 0.f};
        #pragma unroll
        for (int ks = 0; ks < 4; ++ks) {
            int k0 = ks * 32 + kg * 8;
            bfrag a0 = *(const bfrag*)(atile + (wr + lr) * WPAD + k0);
            bfrag a1 = *(const bfrag*)(atile + (wr + 16 + lr) * WPAD + k0);
            #pragma unroll
            for (int nt = 0; nt < 4; ++nt) {
                bfrag b = *(const bfrag*)(wt1 + (wchalf + nt * 16 + lr) * WPAD + k0);
                acc[0][nt] = __builtin_amdgcn_mfma_f32_16x16x32_bf16(a0, b, acc[0][nt], 0, 0, 0);
                acc[1][nt] = __builtin_amdgcn_mfma_f32_16x16x32_bf16(a1, b, acc[1][nt], 0, 0, 0);
            }
        }
        __syncthreads();   // atile reads done, safe to overwrite with h

        #pragma unroll
        for (int m = 0; m < 2; ++m) {
            int rbase = wr + m * 16 + kg * 4;
            #pragma unroll
            for (int nt = 0; nt < 4; ++nt) {
                int col = wchalf + nt * 16 + lr;
                #pragma unroll
                for (int i = 0; i < 4; ++i) {
                    float h = ssp(acc[m][nt][i] + bias1[nt]);
                    atile[(rbase + i) * WPAD + col] = f2bf(h);
                }
            }
        }
        __syncthreads();

        // pass B: out = v + h @ w2 + b2
        facc acc2[2][4];
        #pragma unroll
        for (int m = 0; m < 2; ++m)
            #pragma unroll
            for (int nt = 0; nt < 4; ++nt)
                acc2[m][nt] = (facc){0.f, 0.f, 0.f, 0.f};
        #pragma unroll
        for (int ks = 0; ks < 4; ++ks) {
            int k0 = ks * 32 + kg * 8;
            bfrag a0 = *(const bfrag*)(atile + (wr + lr) * WPAD + k0);
            bfrag a1 = *(const bfrag*)(atile + (wr + 16 + lr) * WPAD + k0);
            #pragma unroll
            for (int nt = 0; nt < 4; ++nt) {
                bfrag b = *(const bfrag*)(wt2 + (wchalf + nt * 16 + lr) * WPAD + k0);
                acc2[0][nt] = __builtin_amdgcn_mfma_f32_16x16x32_bf16(a0, b, acc2[0][nt], 0, 0, 0);
                acc2[1][nt] = __builtin_amdgcn_mfma_f32_16x16x32_bf16(a1, b, acc2[1][nt], 0, 0, 0);
            }
        }

        #pragma unroll
        for (int m = 0; m < 2; ++m) {
            #pragma unroll
            for (int i = 0; i < 4; ++i) {
                int row = base + wr + m * 16 + kg * 4 + i;
                if (row < N) {
                    #pragma unroll
                    for (int nt = 0; nt < 4; ++nt) {
                        int col = wchalf + nt * 16 + lr;
                        out[(size_t)row * HF + col] = acc2[m][nt][i] + bias2[nt] + v[(size_t)row * HF + col];
                    }
                }
            }
        }
    }
}

// ---------------------------------------------------------------------------
// Fallback path (ws too small): atomic scatter + f32 vector MLP
// ---------------------------------------------------------------------------
__global__ void scatter_add_kernel(const float* __restrict__ e,
                                   const int* __restrict__ tgt,
                                   float* __restrict__ agg, int E) {
    int t = blockIdx.x * blockDim.x + threadIdx.x;
    int eid = t >> 5;
    if (eid >= E) return;
    int c = t & 31;
    int dst = tgt[eid];
    float4 val = *reinterpret_cast<const float4*>(e + (size_t)eid * HF + c * 4);
    float* p = agg + (size_t)dst * HF + c * 4;
    unsafeAtomicAdd(p + 0, val.x);
    unsafeAtomicAdd(p + 1, val.y);
    unsafeAtomicAdd(p + 2, val.z);
    unsafeAtomicAdd(p + 3, val.w);
}

__device__ __forceinline__ void fma4(float4& acc, float a, const float4& w) {
    acc.x = fmaf(a, w.x, acc.x);
    acc.y = fmaf(a, w.y, acc.y);
    acc.z = fmaf(a, w.z, acc.z);
    acc.w = fmaf(a, w.w, acc.w);
}

__global__ __launch_bounds__(512) void mlp_kernel(
        float* __restrict__ data, const float* __restrict__ v,
        const float* __restrict__ w1, const float* __restrict__ b1,
        const float* __restrict__ w2, const float* __restrict__ b2, int N) {
    __shared__ float w1s[HF * HF];
    __shared__ float w2s[HF * HF];
    __shared__ float tile[32][HF];
    int tid = threadIdx.x;
    float4* w1sv = (float4*)w1s; float4* w2sv = (float4*)w2s;
    for (int i = tid; i < HF * HF / 4; i += 512) {
        w1sv[i] = ((const float4*)w1)[i];
        w2sv[i] = ((const float4*)w2)[i];
    }
    int nl = tid >> 5, fblk = tid & 31;
    float4 bb1 = ((const float4*)b1)[fblk];
    float4 bb2 = ((const float4*)b2)[fblk];
    float4* tilev = (float4*)tile;
    int ngroups = (N + 31) / 32;
    for (int g = blockIdx.x; g < ngroups; g += gridDim.x) {
        int base = g * 32;
        __syncthreads();
        for (int i = tid; i < 32 * (HF / 4); i += 512) {
            int node = base + (i >> 5);
            float4 val = make_float4(0.f, 0.f, 0.f, 0.f);
            if (node < N) val = ((const float4*)data)[(size_t)node * (HF / 4) + (i & 31)];
            tilev[i] = val;
        }
        __syncthreads();
        float4 a0 = bb1, a1 = bb1;
        #pragma unroll 8
        for (int k = 0; k < HF; ++k) {
            float x0 = tile[nl][k], x1 = tile[nl + 16][k];
            float4 w = w1sv[k * 32 + fblk];
            fma4(a0, x0, w); fma4(a1, x1, w);
        }
        a0.x = ssp(a0.x); a0.y = ssp(a0.y); a0.z = ssp(a0.z); a0.w = ssp(a0.w);
        a1.x = ssp(a1.x); a1.y = ssp(a1.y); a1.z = ssp(a1.z); a1.w = ssp(a1.w);
        __syncthreads();
        tilev[nl * 32 + fblk] = a0;
        tilev[(nl + 16) * 32 + fblk] = a1;
        __syncthreads();
        float4 c0 = bb2, c1 = bb2;
        #pragma unroll 8
        for (int k = 0; k < HF; ++k) {
            float x0 = tile[nl][k], x1 = tile[nl + 16][k];
            float4 w = w2sv[k * 32 + fblk];
            fma4(c0, x0, w); fma4(c1, x1, w);
        }
        int n0 = base + nl, n1 = base + nl + 16;
        if (n0 < N) {
            float4 vv = ((const float4*)v)[(size_t)n0 * 32 + fblk];
            c0.x += vv.x; c0.y += vv.y; c0.z += vv.z; c0.w += vv.w;
            ((float4*)data)[(size_t)n0 * 32 + fblk] = c0;
        }
        if (n1 < N) {
            float4 vv = ((const float4*)v)[(size_t)n1 * 32 + fblk];
            c1.x += vv.x; c1.y += vv.y; c1.z += vv.z; c1.w += vv.w;
            ((float4*)data)[(size_t)n1 * 32 + fblk] = c1;
        }
    }
}

extern "C" void kernel_launch(void* const* d_in, const int* in_sizes, int n_in,
                              void* d_out, int out_size, void* d_ws, size_t ws_size,
                              hipStream_t stream) {
    const float* v  = (const float*)d_in[0];
    const float* e  = (const float*)d_in[1];
    const int*   ei = (const int*)d_in[2];
    const float* w1 = (const float*)d_in[3];
    const float* b1 = (const float*)d_in[4];
    const float* w2 = (const float*)d_in[5];
    const float* b2 = (const float*)d_in[6];
    float* out = (float*)d_out;

    int N = in_sizes[0] / HF;    // 50000
    int E = in_sizes[2] / 2;     // 600000
    const int* tgt = ei + E;     // edge_index[1]

    // ws layout: counts[N] | offsets[N+1] | bsum[64] | pad | es[E*HF bf16] | aggb[N*HF bf16]
    size_t ints = (size_t)N + (N + 1) + 64;
    size_t needed = ints * 4 + 32 + (size_t)E * HF * 2 + (size_t)N * HF * 2;
    if (ws_size >= needed) {
        int* counts  = (int*)d_ws;
        int* offsets = counts + N;
        int* bsum    = offsets + N + 1;
        uintptr_t p = (uintptr_t)(bsum + 64);
        p = (p + 15) & ~(uintptr_t)15;
        unsigned short* es = (unsigned short*)p;
        unsigned short* aggb = es + (size_t)E * HF;

        hipMemsetAsync(counts, 0, (size_t)N * sizeof(int), stream);

        int eb = (E + 255) / 256;
        int nb = (N + 1023) / 1024;   // 49
        hist_kernel<<<eb, 256, 0, stream>>>(tgt, counts, E);
        scan1_kernel<<<nb, 1024, 0, stream>>>(counts, offsets, bsum, N);
        scan23_kernel<<<nb, 1024, 0, stream>>>(offsets, bsum, N, E, nb);

        // stream+convert+scatter: 2 edges per wave, 8 waves... 256 thr = 4 waves = 8 edges/block
        int scb = (E + 7) / 8;
        scatter_convert_kernel<<<scb, 256, 0, stream>>>(e, tgt, offsets, counts, es, E);

        gather_seq_kernel<<<(N + 3) / 4, 256, 0, stream>>>(es, offsets, aggb, N);

        int ngroups = (N + HF - 1) / HF;  // 391
        mlp_mfma_kernel<<<256, 512, 0, stream>>>(aggb, v, w1, b1, w2, b2, out, N, ngroups);
    } else {
        hipMemsetAsync(out, 0, (size_t)N * HF * sizeof(float), stream);
        long long total_t = (long long)E * 32;
        scatter_add_kernel<<<(int)((total_t + 255) / 256), 256, 0, stream>>>(e, tgt, out, E);
        mlp_kernel<<<512, 512, 0, stream>>>(out, v, w1, b1, w2, b2, N);
    }
}